// Round 6
// baseline (321.116 us; speedup 1.0000x reference)
//
#include <hip/hip_runtime.h>
#include <hip/hip_bf16.h>
#include <stdint.h>

#define B_DIM 4096
#define P_DIMC 1024
#define H_DIMC 2048
#define X_DIMC 1024
#define K_DIM 4096   // P + H + X
#define N_DIM 8192   // 4*H, packed: n = (h>>6)*256 + ((h>>4)&3)*16 + gate*64 + (h&15)

#define BM 256
#define BN 256
#define BK 64
#define NT (K_DIM / BK)   // 64 K-tiles

typedef __attribute__((ext_vector_type(8))) short bf16x8;
typedef __attribute__((ext_vector_type(4))) float f32x4;

__device__ __forceinline__ unsigned short f2bf(float f) {
  union { float f; unsigned u; } v; v.f = f;
  unsigned u = v.u;
  u += 0x7FFFu + ((u >> 16) & 1u);   // round-to-nearest-even
  return (unsigned short)(u >> 16);
}

__device__ __forceinline__ float sigm(float x) { return 1.f / (1.f + __expf(-x)); }
__device__ __forceinline__ float tanh_fast(float x) {
  float e = __expf(2.f * x);
  return 1.f - 2.f / (e + 1.f);      // safe at +/- inf
}

__device__ __forceinline__ void gl_lds16(const void* g, void* l) {
  __builtin_amdgcn_global_load_lds((const __attribute__((address_space(1))) void*)g,
                                   (__attribute__((address_space(3))) void*)l, 16, 0, 0);
}

// ---------------- pack A = [P | hidden | ext] -> bf16 [B][K] ----------------
__global__ void pack_a_kernel(const float* __restrict__ P, const float* __restrict__ Hd,
                              const float* __restrict__ X, unsigned short* __restrict__ A) {
  const int total = B_DIM * (K_DIM / 4);
  for (int idx = blockIdx.x * blockDim.x + threadIdx.x; idx < total;
       idx += gridDim.x * blockDim.x) {
    int row = idx >> 10;
    int col = (idx & 1023) << 2;
    const float* src; int off;
    if (col < P_DIMC)                { src = P;  off = row * P_DIMC + col; }
    else if (col < P_DIMC + H_DIMC)  { src = Hd; off = row * H_DIMC + (col - P_DIMC); }
    else                             { src = X;  off = row * X_DIMC + (col - P_DIMC - H_DIMC); }
    float4 v = *(const float4*)(src + off);
    ushort4 o;
    o.x = f2bf(v.x); o.y = f2bf(v.y); o.z = f2bf(v.z); o.w = f2bf(v.w);
    *(ushort4*)(A + (size_t)row * K_DIM + col) = o;
  }
}

// ------- pack Wbig [N][K] bf16 ----------------------------------------------
// row n: gate = (n>>6)&3, h = (n>>8)*64 + ((n>>4)&3)*16 + (n&15)
// (inverse: n = (h>>6)*256 + ((h>>4)&3)*16 + gate*64 + (h&15))
struct WPtrs {
  const float *pi, *pf, *pg, *po;
  const float *hi, *hf, *hg, *ho;
  const float *xi, *xf, *xg, *xo;
};

__global__ void pack_w_kernel(WPtrs w, unsigned short* __restrict__ Wo) {
  const int total = N_DIM * (K_DIM / 4);
  for (int idx = blockIdx.x * blockDim.x + threadIdx.x; idx < total;
       idx += gridDim.x * blockDim.x) {
    int n = idx >> 10;
    int col = (idx & 1023) << 2;
    int gate = (n >> 6) & 3;
    int h = (n >> 8) * 64 + ((n >> 4) & 3) * 16 + (n & 15);
    const float* src; int off;
    if (col < P_DIMC) {
      src = gate == 0 ? w.pi : gate == 1 ? w.pf : gate == 2 ? w.pg : w.po;
      off = h * P_DIMC + col;
    } else if (col < P_DIMC + H_DIMC) {
      src = gate == 0 ? w.hi : gate == 1 ? w.hf : gate == 2 ? w.hg : w.ho;
      off = h * H_DIMC + (col - P_DIMC);
    } else {
      src = gate == 0 ? w.xi : gate == 1 ? w.xf : gate == 2 ? w.xg : w.xo;
      off = h * X_DIMC + (col - P_DIMC - H_DIMC);
    }
    float4 v = *(const float4*)(src + off);
    ushort4 o;
    o.x = f2bf(v.x); o.y = f2bf(v.y); o.z = f2bf(v.z); o.w = f2bf(v.w);
    *(ushort4*)(Wo + (size_t)n * K_DIM + col) = o;
  }
}

// ------ fused GEMM: 256x256 tile, BK=64, 8-phase convoy (m201 structure) ----
// 2-deep dbuf; 4 phases/K-tile; per-phase: reads + 1 half-tile stage +
// barrier-fenced 16-MFMA cluster; FIFO-derived counted vmcnt (never 0 mid-loop).
__global__ __launch_bounds__(512, 1) void gemm_lstm_kernel(
    const unsigned short* __restrict__ A, const unsigned short* __restrict__ W,
    const float* __restrict__ cell,
    const float* __restrict__ bpi, const float* __restrict__ bpf,
    const float* __restrict__ bpg, const float* __restrict__ bpo,
    float* __restrict__ out) {
  // [dbuf][half][128 rows x 64 k] each 16 KB; A 64 KB + B 64 KB = 128 KiB
  __shared__ __align__(16) short As[2][2][8192];
  __shared__ __align__(16) short Bs[2][2][8192];

  const int T = threadIdx.x;
  const int wave = T >> 6, lane = T & 63;
  const int wm = wave >> 2, wn = wave & 3;     // 2 x 4 wave grid

  // XCD-aware mapping: 512 blocks, XCD x gets an 8x8 tile patch
  const int x = blockIdx.x & 7, local = blockIdx.x >> 3;
  const int bm = (x & 1) * 8 + (local >> 3);   // 0..15
  const int bn = (x >> 1) * 8 + (local & 7);   // 0..31

  // ---- staging: linear LDS dest (row rA, slot T&7), pre-swizzled source ----
  // row r (128B = 8 chunks of 16B): logical chunk c stored at slot (c+(r&7))&7
  const int rA = T >> 3;                        // 0..63
  const int cg = ((T & 7) - (rA & 7)) & 7;      // logical chunk this thread fetches
  const unsigned short* aS0 = A + (size_t)(bm * BM + rA) * K_DIM + cg * 8;
  const unsigned short* aS1 = A + (size_t)(bm * BM + 128 + rA) * K_DIM + cg * 8;
  const unsigned short* bS0 = W + (size_t)(bn * BN + rA) * K_DIM + cg * 8;
  const unsigned short* bS1 = W + (size_t)(bn * BN + 128 + rA) * K_DIM + cg * 8;
  const int dOff = T * 8;                       // shorts; +4096 for rows 64-127

  // ---- fragment read addressing ----
  // A frag mf: tile row wm*16 + mf*32 (+lrow)  -> half = mf>>2
  // B frag nf: tile col wn*16 + nf*64 (+lrow)  -> half = nf>>1
  const int lrow = lane & 15, kgrp = lane >> 4;
  const int aRow = (wm * 16 + lrow) * 64;       // shorts, within half
  const int bRow = (wn * 16 + lrow) * 64;
  const int sl0 = ((kgrp + (lrow & 7)) & 7) * 8;        // k32=0 slot
  const int sl1 = ((kgrp + 4 + (lrow & 7)) & 7) * 8;    // k32=1 slot

  f32x4 acc[8][4] = {};
  bf16x8 ra[4][2], rb[2][2];

  // ---- prologue: stage K-tile 0 (Ah0,Bh0,Ah1,Bh1 = 8 loads), wait first 2 halves
  gl_lds16(aS0, &As[0][0][dOff]); gl_lds16(aS0 + (size_t)64 * K_DIM, &As[0][0][4096 + dOff]);
  gl_lds16(bS0, &Bs[0][0][dOff]); gl_lds16(bS0 + (size_t)64 * K_DIM, &Bs[0][0][4096 + dOff]);
  gl_lds16(aS1, &As[0][1][dOff]); gl_lds16(aS1 + (size_t)64 * K_DIM, &As[0][1][4096 + dOff]);
  gl_lds16(bS1, &Bs[0][1][dOff]); gl_lds16(bS1 + (size_t)64 * K_DIM, &Bs[0][1][4096 + dOff]);
  asm volatile("s_waitcnt vmcnt(4)" ::: "memory");
  __builtin_amdgcn_s_barrier();

#define RD_A(HALF)                                                            \
  _Pragma("unroll") for (int i = 0; i < 4; ++i) {                             \
    ra[i][0] = *(const bf16x8*)(&As[cur][HALF][0] + aRow + i * 2048 + sl0);   \
    ra[i][1] = *(const bf16x8*)(&As[cur][HALF][0] + aRow + i * 2048 + sl1);   \
  }
#define RD_B(HALF)                                                            \
  _Pragma("unroll") for (int j = 0; j < 2; ++j) {                             \
    rb[j][0] = *(const bf16x8*)(&Bs[cur][HALF][0] + bRow + j * 4096 + sl0);   \
    rb[j][1] = *(const bf16x8*)(&Bs[cur][HALF][0] + bRow + j * 4096 + sl1);   \
  }
#define MFMA16(MH, NH)                                                        \
  __builtin_amdgcn_s_setprio(1);                                              \
  _Pragma("unroll") for (int i = 0; i < 4; ++i)                               \
  _Pragma("unroll") for (int j = 0; j < 2; ++j) {                             \
    acc[(MH)*4 + i][(NH)*2 + j] = __builtin_amdgcn_mfma_f32_16x16x32_bf16(    \
        ra[i][0], rb[j][0], acc[(MH)*4 + i][(NH)*2 + j], 0, 0, 0);            \
    acc[(MH)*4 + i][(NH)*2 + j] = __builtin_amdgcn_mfma_f32_16x16x32_bf16(    \
        ra[i][1], rb[j][1], acc[(MH)*4 + i][(NH)*2 + j], 0, 0, 0);            \
  }                                                                           \
  __builtin_amdgcn_s_setprio(0);                                              \
  __builtin_amdgcn_sched_barrier(0);
#define FENCE_IN()                                                            \
  __builtin_amdgcn_s_barrier();                                               \
  asm volatile("s_waitcnt lgkmcnt(0)" ::: "memory");                          \
  __builtin_amdgcn_sched_barrier(0);
#define STAGE(SRC, DARR, NXT, HALF)                                           \
  { const unsigned short* s_ = (SRC) + ktn * BK;                              \
    gl_lds16(s_, &DARR[NXT][HALF][dOff]);                                     \
    gl_lds16(s_ + (size_t)64 * K_DIM, &DARR[NXT][HALF][4096 + dOff]); }

  for (int t = 0; t < NT; ++t) {
    const int cur = t & 1, nxt = cur ^ 1;
    const int ktn = t + 1;
    const bool st = (t < NT - 1);

    // ---- phase 0: m0-3 x n0-1 (A-h0, B-h0); stage Ah0(t+1) ----
    RD_A(0) RD_B(0)
    if (st) STAGE(aS0, As, nxt, 0)
    FENCE_IN()
    MFMA16(0, 0)
    if (st) { asm volatile("s_waitcnt vmcnt(4)" ::: "memory"); }  // Ah1(t) landed
    else    { asm volatile("s_waitcnt vmcnt(2)" ::: "memory"); }
    __builtin_amdgcn_s_barrier();

    // ---- phase 1: m4-7 x n0-1 (A-h1, B-h0 held); stage Bh0(t+1) ----
    RD_A(1)
    if (st) STAGE(bS0, Bs, nxt, 0)
    FENCE_IN()
    MFMA16(1, 0)
    if (st) { asm volatile("s_waitcnt vmcnt(4)" ::: "memory"); }  // Bh1(t) landed
    else    { asm volatile("s_waitcnt vmcnt(0)" ::: "memory"); }
    __builtin_amdgcn_s_barrier();

    // ---- phase 2: m4-7 x n2-3 (A-h1 held, B-h1); stage Ah1(t+1) ----
    RD_B(1)
    if (st) STAGE(aS1, As, nxt, 1)
    FENCE_IN()
    MFMA16(1, 1)
    __builtin_amdgcn_s_barrier();

    // ---- phase 3: m0-3 x n2-3 (A-h0 re-read, B-h1 held); stage Bh1(t+1) ----
    RD_A(0)
    if (st) STAGE(bS1, Bs, nxt, 1)
    FENCE_IN()
    MFMA16(0, 1)
    if (st) { asm volatile("s_waitcnt vmcnt(4)" ::: "memory"); }  // Ah0,Bh0(t+1) landed
    __builtin_amdgcn_s_barrier();
  }
#undef RD_A
#undef RD_B
#undef MFMA16
#undef FENCE_IN
#undef STAGE

  // ---- fused LSTM epilogue (per-lane: n-frags 0..3 = gates i,f,g,o of h) ---
  const int h = bn * 64 + wn * 16 + lrow;
  const float bi = bpi[h], bf_ = bpf[h], bg = bpg[h], bo = bpo[h];
  const int rbase = bm * BM + wm * 16 + kgrp * 4;
#pragma unroll
  for (int mf = 0; mf < 8; ++mf) {
#pragma unroll
    for (int r = 0; r < 4; ++r) {
      const int brow = rbase + mf * 32 + r;
      float gi = acc[mf][0][r] + bi;
      float gf = acc[mf][1][r] + bf_;
      float gg = acc[mf][2][r] + bg;
      float go = acc[mf][3][r] + bo;
      float i_ = sigm(gi), f_ = sigm(gf), g_ = tanh_fast(gg), o_ = sigm(go);
      float cold = cell[(size_t)brow * H_DIMC + h];
      float cn = f_ * cold + i_ * g_;
      out[(size_t)brow * H_DIMC + h] = o_ * tanh_fast(cn);
      out[(size_t)B_DIM * H_DIMC + (size_t)brow * H_DIMC + h] = cn;
    }
  }
}

extern "C" void kernel_launch(void* const* d_in, const int* in_sizes, int n_in,
                              void* d_out, int out_size, void* d_ws, size_t ws_size,
                              hipStream_t stream) {
  const float* P    = (const float*)d_in[0];
  const float* Hd   = (const float*)d_in[1];
  const float* cell = (const float*)d_in[2];
  const float* X    = (const float*)d_in[3];
  WPtrs w;
  w.pi = (const float*)d_in[4];   const float* bpi = (const float*)d_in[5];
  w.pf = (const float*)d_in[6];   const float* bpf = (const float*)d_in[7];
  w.pg = (const float*)d_in[8];   const float* bpg = (const float*)d_in[9];
  w.po = (const float*)d_in[10];  const float* bpo = (const float*)d_in[11];
  w.hi = (const float*)d_in[12];  w.hf = (const float*)d_in[13];
  w.hg = (const float*)d_in[14];  w.ho = (const float*)d_in[15];
  w.xi = (const float*)d_in[16];  w.xf = (const float*)d_in[17];
  w.xg = (const float*)d_in[18];  w.xo = (const float*)d_in[19];

  unsigned short* Abf = (unsigned short*)d_ws;                 // 32 MiB
  unsigned short* Wbf = Abf + (size_t)B_DIM * K_DIM;           // 64 MiB

  pack_a_kernel<<<2048, 256, 0, stream>>>(P, Hd, X, Abf);
  pack_w_kernel<<<2048, 256, 0, stream>>>(w, Wbf);
  gemm_lstm_kernel<<<512, 512, 0, stream>>>(Abf, Wbf, cell, bpi, bpf, bpg, bpo,
                                            (float*)d_out);
}